// Round 12
// baseline (42.408 us; speedup 1.0000x reference)
//
#include <hip/hip_runtime.h>
#include <hip/hip_bf16.h>

typedef int i32x4 __attribute__((ext_vector_type(4)));
typedef int i32x8 __attribute__((ext_vector_type(8)));
typedef float f32x4 __attribute__((ext_vector_type(4)));

#define KD 768
#define BDIM 4096
#define NSTRIP 8         // 512 cols / 64
#define E8M0_1_8TH 124   // 2^(124-127) = 1/8
#define BLDS 49152       // 64 cols x 768 K bytes

#define GLOAD_LDS16(gptr, lptr)                                             \
    __builtin_amdgcn_global_load_lds(                                       \
        (const __attribute__((address_space(1))) unsigned int*)(gptr),      \
        (__attribute__((address_space(3))) unsigned int*)(lptr), 16, 0, 0)

#define FBAR() asm volatile("s_barrier" ::: "memory")
#define SCHED_FENCE() __builtin_amdgcn_sched_barrier(0)

__device__ inline unsigned char f32_to_e4m3(float f) {
    int p = __builtin_amdgcn_cvt_pk_fp8_f32(f, f, 0, false);
    return (unsigned char)(p & 0xFF);
}

// ---------------- Kernel 1: row-normalize fp32 -> fp8 e4m3, pre-scaled x8 ----------------
__global__ __launch_bounds__(256) void normalize_rows_fp8(
    const float* __restrict__ x, unsigned char* __restrict__ xn)
{
    const int row = blockIdx.x;
    const int t = threadIdx.x;
    const float* xr = x + (long)row * KD;

    float v[3];
    float ss = 0.f;
#pragma unroll
    for (int i = 0; i < 3; ++i) {
        v[i] = xr[t + 256 * i];
        ss += v[i] * v[i];
    }
#pragma unroll
    for (int off = 32; off > 0; off >>= 1) ss += __shfl_down(ss, off);
    __shared__ float wss[4];
    const int lane = t & 63, wv = t >> 6;
    if (lane == 0) wss[wv] = ss;
    __syncthreads();
    const float tot = wss[0] + wss[1] + wss[2] + wss[3];
    const float inv = 8.0f / fmaxf(sqrtf(tot), 1e-8f);
#pragma unroll
    for (int i = 0; i < 3; ++i)
        xn[(long)row * KD + t + 256 * i] = f32_to_e4m3(v[i] * inv);
}

// ---------------- Kernel 2: streaming MX-fp8 GEMM, 64-col strips ----------------
// WRITE-LOCALITY CHANGE vs R11: block = 128 rows x 512 cols, strips of 64 cols
// (NSTRIP=8). Per strip a block writes 128 rows x 512 B runs (was 64 x 256 B)
// -> 2x longer, temporally denser HBM write runs. B-LDS 3 x 48 KB = 144 KB,
// 1 block/CU. Uniform vmcnt(16): exact FIFO count — ops younger than B(s+1)
// are >= 22 everywhere, so <=16 outstanding guarantees B(s+1) landed and never
// waits on the current strip's 16 stores.
// 8 waves (4M x 2N): wave = 32 rows x 32 cols/strip; per strip per wave:
// 24 ds_read_b128, 24 MFMA(K=128... 2mf x 2nf x 6kk), 16 float2 stores.
__global__ __launch_bounds__(512, 2) void sim_gemm_stream(
    const unsigned char* __restrict__ Xn,
    const float* __restrict__ fcw, const float* __restrict__ fcb,
    float* __restrict__ out)
{
    __shared__ __align__(16) unsigned char Bb[3][BLDS];  // 3 x 48 KB

    const int tid = threadIdx.x;
    const int wv  = tid >> 6;    // 0..7
    const int ln  = tid & 63;
    const int wm  = wv >> 1;     // 0..3 (M group, 32 rows)
    const int wn  = wv & 1;      // 0..1 (N group, 32 cols)
    const int fr  = ln & 15;
    const int q   = ln >> 4;     // 0..3

    const int jc = blockIdx.x;   // 0..7   col chunk (512 cols)
    const int bi = blockIdx.y;   // 0..31  row chunk (128 rows)
    const long Arow0 = (long)bi * 128;
    const long Bcol0 = (long)jc * 512;

    // --- B staging precompute: dest byte d = i*8192 + tid*16, i<6.
    //     d -> kk=d>>13, o=(d>>12)&1, col=(d>>6)&63, q=(d>>4)&3
    //     source: Xn row (Bcol0+s*64+col), k byte = kk*128+q*32+o*16 (16B contiguous)
    int scol[6], skoff[6];
#pragma unroll
    for (int i = 0; i < 6; ++i) {
        const int d = i * 8192 + tid * 16;
        scol[i]  = (d >> 6) & 63;
        skoff[i] = ((d >> 13) << 7) + (((d >> 4) & 3) << 5) + (((d >> 12) & 1) << 4);
    }

#define ISSUE_B(s) do {                                                      \
        _Pragma("unroll")                                                    \
        for (int i_ = 0; i_ < 6; ++i_) {                                     \
            const unsigned char* g_ = Xn                                     \
                + (Bcol0 + (s) * 64 + scol[i_]) * (long)KD + skoff[i_];      \
            unsigned char* l_ = &Bb[(s) % 3][0] + i_ * 8192 + wv * 1024;     \
            GLOAD_LDS16(g_, l_);                                             \
        }                                                                    \
    } while (0)

    // --- A fragments: global -> registers, once. 2 M-frags x 6 kk x 32 B = 96 VGPR.
    i32x8 aF[2][6];
    {
        const unsigned char* pa0 = Xn + (Arow0 + wm * 32 + fr) * (long)KD + q * 32;
        const unsigned char* pa1 = pa0 + 16 * (long)KD;
#pragma unroll
        for (int kk = 0; kk < 6; ++kk) {
            i32x4 lo0 = *(const i32x4*)(pa0 + kk * 128);
            i32x4 hi0 = *(const i32x4*)(pa0 + kk * 128 + 16);
            aF[0][kk] = __builtin_shufflevector(lo0, hi0, 0, 1, 2, 3, 4, 5, 6, 7);
            i32x4 lo1 = *(const i32x4*)(pa1 + kk * 128);
            i32x4 hi1 = *(const i32x4*)(pa1 + kk * 128 + 16);
            aF[1][kk] = __builtin_shufflevector(lo1, hi1, 0, 1, 2, 3, 4, 5, 6, 7);
        }
    }

    const float w0 = fcw[0], w1 = fcw[1];
    const float c0 = fcb[0], c1 = fcb[1];

    // --- prologue: stage strips 0,1; wait strip 0 (6 youngest = B(1)); sync ---
    ISSUE_B(0);
    ISSUE_B(1);
    asm volatile("s_waitcnt vmcnt(6)" ::: "memory");
    FBAR();

    const int colb0 = (int)Bcol0 + wn * 32 + fr;
    const long rowb = Arow0 + wm * 32 + q * 4;

    for (int s = 0; s < NSTRIP; ++s) {
        const int bb = s % 3;

        if (s + 2 < NSTRIP) ISSUE_B(s + 2);  // into (s+2)%3 == (s-1)%3: reads done
        SCHED_FENCE();  // pin order: staging loads issue before this strip's stores

        // compute strip: 2 mf x 2 nf frags, 6-kk chain each (order as R11)
        f32x4 acc[2][2] = {};
#pragma unroll
        for (int kk = 0; kk < 6; ++kk) {
#pragma unroll
            for (int nf = 0; nf < 2; ++nf) {
                const int bo = kk * 8192 + (wn * 32 + nf * 16 + fr) * 64 + q * 16;
                i32x4 lo = *(const i32x4*)&Bb[bb][bo];
                i32x4 hi = *(const i32x4*)&Bb[bb][bo + 4096];
                i32x8 bv = __builtin_shufflevector(lo, hi, 0, 1, 2, 3, 4, 5, 6, 7);
                __builtin_amdgcn_s_setprio(1);
                acc[0][nf] = __builtin_amdgcn_mfma_scale_f32_16x16x128_f8f6f4(
                    aF[0][kk], bv, acc[0][nf], 0, 0, 0, E8M0_1_8TH, 0, E8M0_1_8TH);
                acc[1][nf] = __builtin_amdgcn_mfma_scale_f32_16x16x128_f8f6f4(
                    aF[1][kk], bv, acc[1][nf], 0, 0, 0, E8M0_1_8TH, 0, E8M0_1_8TH);
                __builtin_amdgcn_s_setprio(0);
            }
        }

        // stream this strip's output: 16 float2 stores/lane
        const int col = colb0 + s * 64;
#pragma unroll
        for (int mf = 0; mf < 2; ++mf)
#pragma unroll
            for (int nf = 0; nf < 2; ++nf)
#pragma unroll
                for (int rr = 0; rr < 4; ++rr) {
                    const long row = rowb + mf * 16 + rr;
                    const float sv = acc[mf][nf][rr];
                    *(float2*)&out[(row * BDIM + col + nf * 16) * 2] =
                        make_float2(fmaf(sv, w0, c0), fmaf(sv, w1, c1));
                }

        if (s + 1 < NSTRIP) {
            // FIFO: ops younger than B(s+1)'s loads >= 22 everywhere;
            // vmcnt(16) => B(s+1) landed; current strip's 16 stores may remain.
            asm volatile("s_waitcnt vmcnt(16)" ::: "memory");
            FBAR();
        }
    }

#undef ISSUE_B
}

extern "C" void kernel_launch(void* const* d_in, const int* in_sizes, int n_in,
                              void* d_out, int out_size, void* d_ws, size_t ws_size,
                              hipStream_t stream) {
    const float* x   = (const float*)d_in[0];
    const float* fcw = (const float*)d_in[1];
    const float* fcb = (const float*)d_in[2];
    float* out = (float*)d_out;

    unsigned char* xn = (unsigned char*)d_ws;  // 4096*768*1B = 3.1 MB

    normalize_rows_fp8<<<BDIM, 256, 0, stream>>>(x, xn);

    dim3 grid(8, 32);  // jc x bi = 256 blocks, 1/CU
    sim_gemm_stream<<<grid, 512, 0, stream>>>(xn, fcw, fcb, out);
}